// Round 1
// baseline (1111.842 us; speedup 1.0000x reference)
//
#include <hip/hip_runtime.h>
#include <hip/hip_bf16.h>

// Problem constants (fixed by the reference)
constexpr int B  = 8;
constexpr int C  = 1024;
constexpr int T  = 512;
constexpr int HW = 49;     // 7*7 spatial
constexpr int D  = 128;    // sim_dim == out_dim
constexpr int LW = 101;    // lookup window
constexpr int HALF = 50;   // (LW-1)/2

// ---------------------------------------------------------------------------
// Kernel 1: spatial mean. inputs [B,C,T,7,7] -> xm [B,C,T]
// Each block: 256 groups x 49 floats = 50176 B contiguous, staged via float4
// into LDS, then per-thread stride-49 reduction (gcd(49,32)=1, conflict-free).
// ---------------------------------------------------------------------------
__global__ __launch_bounds__(256) void mean_kernel(const float* __restrict__ in,
                                                   float* __restrict__ xm) {
    __shared__ float lds[256 * HW];  // 12544 floats = 50176 B
    const int tid = threadIdx.x;
    const long long base = (long long)blockIdx.x * (256 * HW);

    const float4* in4 = (const float4*)(in + base);
    float4* lds4 = (float4*)lds;
    // 12544 floats = 3136 float4 = 12.25 per thread
#pragma unroll
    for (int k = 0; k < 12; ++k) {
        const int j = tid + k * 256;
        lds4[j] = in4[j];
    }
    if (tid < 64) lds4[3072 + tid] = in4[3072 + tid];
    __syncthreads();

    float s = 0.f;
#pragma unroll
    for (int j = 0; j < HW; ++j) s += lds[tid * HW + j];
    xm[(long long)blockIdx.x * 256 + tid] = s * (1.0f / 49.0f);
}

// ---------------------------------------------------------------------------
// Kernel 2: projection + bias + L2 normalize.
// xm [B,C,T] (A^T layout), pw [C,D], pb [D] -> y [B,T,D] normalized.
// Block: 32 t-values x 128 d-values; grid (T/32, B). K-loop over C in 64-steps.
// Thread map: tl = tid&31 (t), dg = tid>>5 (d-group of 16).
// ---------------------------------------------------------------------------
__global__ __launch_bounds__(256) void proj_kernel(const float* __restrict__ xm,
                                                   const float* __restrict__ pw,
                                                   const float* __restrict__ pb,
                                                   float* __restrict__ y) {
    __shared__ float xmt[64][32];    // 8 KB
    __shared__ float pwt[64][128];   // 32 KB
    __shared__ float normp[32][8];   // 1 KB

    const int tid = threadIdx.x;
    const int t0  = blockIdx.x * 32;
    const int b   = blockIdx.y;
    const int tl  = tid & 31;
    const int dg  = tid >> 5;   // 0..7
    const int d0  = dg * 16;

    float acc[16];
#pragma unroll
    for (int j = 0; j < 16; ++j) acc[j] = pb[d0 + j];

    for (int c0 = 0; c0 < C; c0 += 64) {
        __syncthreads();
        // stage xm tile: 64 c x 32 t = 2048 floats (coalesced 32-float runs)
#pragma unroll
        for (int k = 0; k < 8; ++k) {
            const int j  = tid + k * 256;
            const int cc = j >> 5, tt = j & 31;
            xmt[cc][tt] = xm[((long long)b * C + c0 + cc) * T + t0 + tt];
        }
        // stage pw tile: 64 c x 128 d = 2048 float4 (fully coalesced)
#pragma unroll
        for (int k = 0; k < 8; ++k) {
            const int j  = tid + k * 256;
            const int cc = j >> 5, dd = (j & 31) * 4;
            *(float4*)&pwt[cc][dd] = *(const float4*)&pw[(long long)(c0 + cc) * D + dd];
        }
        __syncthreads();
#pragma unroll 4
        for (int cc = 0; cc < 64; ++cc) {
            const float a = xmt[cc][tl];       // broadcast across half-waves
#pragma unroll
            for (int j = 0; j < 16; ++j) acc[j] += a * pwt[cc][d0 + j];
        }
    }

    // L2 norm over d (8 partials per t)
    float p = 0.f;
#pragma unroll
    for (int j = 0; j < 16; ++j) p += acc[j] * acc[j];
    normp[tl][dg] = p;
    __syncthreads();
    float s = 0.f;
#pragma unroll
    for (int k = 0; k < 8; ++k) s += normp[tl][k];
    const float scale = 1.0f / fmaxf(sqrtf(s), 1e-12f);

    float* yo = y + ((long long)b * T + t0 + tl) * D + d0;
#pragma unroll
    for (int j = 0; j < 16; j += 4) {
        float4 v = make_float4(acc[j] * scale, acc[j + 1] * scale,
                               acc[j + 2] * scale, acc[j + 3] * scale);
        *(float4*)&yo[j] = v;
    }
}

// ---------------------------------------------------------------------------
// Kernel 3: banded cosine-sim + FC + ReLU.
// band[b,t,w] = dot(y[b,t,:], y[b,t+w-50,:]) (zero outside [0,T))
// out[b,t,d]  = relu(sum_w band*fcw[w,d] + fcb[d])
// Block: Tt=8 t-values; stage y rows [t0-50, t0+57] (108 rows) in LDS,
// stride padded to 132 floats (16B-aligned, conflict-tamed).
// ---------------------------------------------------------------------------
constexpr int TT    = 8;            // t-tile
constexpr int ROWS  = TT + 2 * HALF;  // 108
constexpr int YPAD  = 132;          // padded row stride (floats)

__global__ __launch_bounds__(256) void band_fc_kernel(const float* __restrict__ y,
                                                      const float* __restrict__ fcw,
                                                      const float* __restrict__ fcb,
                                                      float* __restrict__ out) {
    __shared__ float ybuf[ROWS][YPAD];     // 108*132*4 = 57024 B
    __shared__ float band[TT][LW];         // 8*101*4   = 3232 B

    const int tid = threadIdx.x;
    const int t0  = blockIdx.x * TT;
    const int b   = blockIdx.y;

    // stage y rows (zero-fill out of range): 108*32 = 3456 float4
    for (int j = tid; j < ROWS * 32; j += 256) {
        const int row = j >> 5;
        const int dd  = (j & 31) * 4;
        const int s   = t0 - HALF + row;
        float4 v = make_float4(0.f, 0.f, 0.f, 0.f);
        if (s >= 0 && s < T) v = *(const float4*)&y[((long long)b * T + s) * D + dd];
        *(float4*)&ybuf[row][dd] = v;
    }
    __syncthreads();

    // band dots: 8*101 = 808; map tl = j&7 (fixed per thread), w = j>>3
    for (int j = tid; j < TT * LW; j += 256) {
        const int tl = j & 7;
        const int w  = j >> 3;
        const float* a = ybuf[tl + HALF];
        const float* c = ybuf[tl + w];
        float s = 0.f;
#pragma unroll
        for (int d = 0; d < D; d += 4) {
            const float4 av = *(const float4*)&a[d];
            const float4 cv = *(const float4*)&c[d];
            s += av.x * cv.x + av.y * cv.y + av.z * cv.z + av.w * cv.w;
        }
        band[tl][w] = s;
    }
    __syncthreads();

    // FC + ReLU: thread -> (tl = tid>>5, d0 = (tid&31)*4), float4 everything
    const int tl = tid >> 5;
    const int d0 = (tid & 31) * 4;
    float4 acc = *(const float4*)&fcb[d0];
    for (int w = 0; w < LW; ++w) {
        const float bv = band[tl][w];                        // LDS broadcast
        const float4 fw = *(const float4*)&fcw[(long long)w * D + d0];  // L2-resident
        acc.x += bv * fw.x; acc.y += bv * fw.y;
        acc.z += bv * fw.z; acc.w += bv * fw.w;
    }
    acc.x = fmaxf(acc.x, 0.f); acc.y = fmaxf(acc.y, 0.f);
    acc.z = fmaxf(acc.z, 0.f); acc.w = fmaxf(acc.w, 0.f);
    *(float4*)&out[((long long)b * T + t0 + tl) * D + d0] = acc;
}

// ---------------------------------------------------------------------------
extern "C" void kernel_launch(void* const* d_in, const int* in_sizes, int n_in,
                              void* d_out, int out_size, void* d_ws, size_t ws_size,
                              hipStream_t stream) {
    const float* inputs = (const float*)d_in[0];  // [B,C,T,7,7]
    const float* proj_w = (const float*)d_in[1];  // [C,D]
    const float* proj_b = (const float*)d_in[2];  // [D]
    const float* fc_w   = (const float*)d_in[3];  // [LW,D]
    const float* fc_b   = (const float*)d_in[4];  // [D]
    float* out = (float*)d_out;                   // [B,T,D]

    float* xm = (float*)d_ws;                     // [B,C,T] = 4194304 floats (16 MB)
    float* y  = xm + (long long)B * C * T;        // [B,T,D] = 524288 floats (2 MB)

    // K1: B*C*T/256 = 16384 blocks
    mean_kernel<<<16384, 256, 0, stream>>>(inputs, xm);
    // K2: (T/32, B) = (16, 8)
    proj_kernel<<<dim3(T / 32, B), 256, 0, stream>>>(xm, proj_w, proj_b, y);
    // K3: (T/8, B) = (64, 8)
    band_fc_kernel<<<dim3(T / TT, B), 256, 0, stream>>>(y, fc_w, fc_b, out);
}

// Round 2
// 1087.482 us; speedup vs baseline: 1.0224x; 1.0224x over previous
//
#include <hip/hip_runtime.h>
#include <hip/hip_bf16.h>

// Problem constants (fixed by the reference)
constexpr int B  = 8;
constexpr int C  = 1024;
constexpr int T  = 512;
constexpr int HW = 49;     // 7*7 spatial
constexpr int D  = 128;    // sim_dim == out_dim
constexpr int LW = 101;    // lookup window
constexpr int HALF = 50;   // (LW-1)/2

// ---------------------------------------------------------------------------
// Kernel 1: spatial mean. inputs [B,C,T,7,7] -> xm [B,C,T]
// Each block: 256 groups x 49 floats = 50176 B contiguous, staged via float4
// into LDS, then per-thread stride-49 reduction (49*lane mod 32 -> 2-way max,
// free). ~135 us = HBM floor for 822 MB read.
// ---------------------------------------------------------------------------
__global__ __launch_bounds__(256) void mean_kernel(const float* __restrict__ in,
                                                   float* __restrict__ xm) {
    __shared__ float lds[256 * HW];  // 12544 floats = 50176 B
    const int tid = threadIdx.x;
    const long long base = (long long)blockIdx.x * (256 * HW);

    const float4* in4 = (const float4*)(in + base);
    float4* lds4 = (float4*)lds;
#pragma unroll
    for (int k = 0; k < 12; ++k) {
        const int j = tid + k * 256;
        lds4[j] = in4[j];
    }
    if (tid < 64) lds4[3072 + tid] = in4[3072 + tid];
    __syncthreads();

    float s = 0.f;
#pragma unroll
    for (int j = 0; j < HW; ++j) s += lds[tid * HW + j];
    xm[(long long)blockIdx.x * 256 + tid] = s * (1.0f / 49.0f);
}

// ---------------------------------------------------------------------------
// Kernel 2: projection + bias + L2 normalize (register-tiled v2).
// xm [B,C,T], pw [C,D], pb [D] -> y [B,T,D] normalized.
// Block: 16 t x 128 d, grid (T/16, B) = 256 blocks (1/CU, full chip).
// Thread tile: 2t x 4d -> per K-step: 2 LDS broadcasts + 1 ds_read_b128
// for 16 FMA (2.67 FMA/float vs 0.94 in v1 -> ~4x less LDS traffic).
// ---------------------------------------------------------------------------
constexpr int K2_TT = 16;
constexpr int K2_CC = 64;

__global__ __launch_bounds__(256) void proj_kernel(const float* __restrict__ xm,
                                                   const float* __restrict__ pw,
                                                   const float* __restrict__ pb,
                                                   float* __restrict__ y) {
    __shared__ float xmt[K2_CC][K2_TT];   // 4 KB
    __shared__ float pwt[K2_CC][D];       // 32 KB
    __shared__ float normp[K2_TT][32];    // 2 KB

    const int tid = threadIdx.x;
    const int t0  = blockIdx.x * K2_TT;
    const int b   = blockIdx.y;
    const int tg  = tid >> 5;    // 0..7
    const int dg  = tid & 31;    // 0..31
    const int d0  = dg * 4;
    const int tA  = tg * 2, tB = tA + 1;

    float4 accA = *(const float4*)&pb[d0];
    float4 accB = accA;

    for (int c0 = 0; c0 < C; c0 += K2_CC) {
        __syncthreads();
        // stage xm tile: 64 cc x 16 t = 256 float4 (1 per thread)
        {
            const int cc = tid >> 2, t4 = (tid & 3) * 4;
            *(float4*)&xmt[cc][t4] =
                *(const float4*)&xm[((long long)b * C + c0 + cc) * T + t0 + t4];
        }
        // stage pw tile: 64 cc x 128 d = 2048 float4 (8 per thread, coalesced)
#pragma unroll
        for (int k = 0; k < 8; ++k) {
            const int j  = tid + k * 256;
            const int cc = j >> 5, dd = (j & 31) * 4;
            *(float4*)&pwt[cc][dd] = *(const float4*)&pw[(long long)(c0 + cc) * D + dd];
        }
        __syncthreads();
#pragma unroll 8
        for (int cc = 0; cc < K2_CC; ++cc) {
            const float  aA = xmt[cc][tA];      // broadcast (2 addrs/wave)
            const float  aB = xmt[cc][tB];
            const float4 w  = *(const float4*)&pwt[cc][d0];  // b128, conflict-free
            accA.x += aA * w.x; accA.y += aA * w.y;
            accA.z += aA * w.z; accA.w += aA * w.w;
            accB.x += aB * w.x; accB.y += aB * w.y;
            accB.z += aB * w.z; accB.w += aB * w.w;
        }
    }

    // L2 norm over d: 32 partials per t
    normp[tA][dg] = accA.x*accA.x + accA.y*accA.y + accA.z*accA.z + accA.w*accA.w;
    normp[tB][dg] = accB.x*accB.x + accB.y*accB.y + accB.z*accB.z + accB.w*accB.w;
    __syncthreads();
    float sA = 0.f, sB = 0.f;
#pragma unroll
    for (int k = 0; k < 32; ++k) { sA += normp[tA][k]; sB += normp[tB][k]; }
    const float scA = 1.0f / fmaxf(sqrtf(sA), 1e-12f);
    const float scB = 1.0f / fmaxf(sqrtf(sB), 1e-12f);

    float* yoA = y + ((long long)b * T + t0 + tA) * D + d0;
    float* yoB = y + ((long long)b * T + t0 + tB) * D + d0;
    *(float4*)yoA = make_float4(accA.x * scA, accA.y * scA, accA.z * scA, accA.w * scA);
    *(float4*)yoB = make_float4(accB.x * scB, accB.y * scB, accB.z * scB, accB.w * scB);
}

// ---------------------------------------------------------------------------
// Kernel 3: banded cosine-sim + FC + ReLU.
// band[b,t,w] = dot(y[b,t,:], y[b,t+w-50,:]) (zero outside [0,T))
// out[b,t,d]  = relu(sum_w band*fcw[w,d] + fcb[d])
// ---------------------------------------------------------------------------
constexpr int TT    = 8;              // t-tile
constexpr int ROWS  = TT + 2 * HALF;  // 108
constexpr int YPAD  = 132;            // padded row stride (floats)

__global__ __launch_bounds__(256) void band_fc_kernel(const float* __restrict__ y,
                                                      const float* __restrict__ fcw,
                                                      const float* __restrict__ fcb,
                                                      float* __restrict__ out) {
    __shared__ float ybuf[ROWS][YPAD];     // 57024 B
    __shared__ float band[TT][LW];         // 3232 B

    const int tid = threadIdx.x;
    const int t0  = blockIdx.x * TT;
    const int b   = blockIdx.y;

    // stage y rows (zero-fill out of range): 108*32 = 3456 float4
    for (int j = tid; j < ROWS * 32; j += 256) {
        const int row = j >> 5;
        const int dd  = (j & 31) * 4;
        const int s   = t0 - HALF + row;
        float4 v = make_float4(0.f, 0.f, 0.f, 0.f);
        if (s >= 0 && s < T) v = *(const float4*)&y[((long long)b * T + s) * D + dd];
        *(float4*)&ybuf[row][dd] = v;
    }
    __syncthreads();

    // band dots: 8*101 = 808; tl = j&7 fixed per thread, w = j>>3
    for (int j = tid; j < TT * LW; j += 256) {
        const int tl = j & 7;
        const int w  = j >> 3;
        const float* a = ybuf[tl + HALF];
        const float* c = ybuf[tl + w];
        float s = 0.f;
#pragma unroll
        for (int d = 0; d < D; d += 4) {
            const float4 av = *(const float4*)&a[d];
            const float4 cv = *(const float4*)&c[d];
            s += av.x * cv.x + av.y * cv.y + av.z * cv.z + av.w * cv.w;
        }
        band[tl][w] = s;
    }
    __syncthreads();

    // FC + ReLU: tl = tid>>5, d0 = (tid&31)*4
    const int tl = tid >> 5;
    const int d0 = (tid & 31) * 4;
    float4 acc = *(const float4*)&fcb[d0];
    for (int w = 0; w < LW; ++w) {
        const float  bv = band[tl][w];                        // LDS broadcast
        const float4 fw = *(const float4*)&fcw[(long long)w * D + d0];  // L2-resident
        acc.x += bv * fw.x; acc.y += bv * fw.y;
        acc.z += bv * fw.z; acc.w += bv * fw.w;
    }
    acc.x = fmaxf(acc.x, 0.f); acc.y = fmaxf(acc.y, 0.f);
    acc.z = fmaxf(acc.z, 0.f); acc.w = fmaxf(acc.w, 0.f);
    *(float4*)&out[((long long)b * T + t0 + tl) * D + d0] = acc;
}

// ---------------------------------------------------------------------------
extern "C" void kernel_launch(void* const* d_in, const int* in_sizes, int n_in,
                              void* d_out, int out_size, void* d_ws, size_t ws_size,
                              hipStream_t stream) {
    const float* inputs = (const float*)d_in[0];  // [B,C,T,7,7]
    const float* proj_w = (const float*)d_in[1];  // [C,D]
    const float* proj_b = (const float*)d_in[2];  // [D]
    const float* fc_w   = (const float*)d_in[3];  // [LW,D]
    const float* fc_b   = (const float*)d_in[4];  // [D]
    float* out = (float*)d_out;                   // [B,T,D]

    float* xm = (float*)d_ws;                     // [B,C,T] (16 MB)
    float* y  = xm + (long long)B * C * T;        // [B,T,D] (2 MB)

    mean_kernel<<<16384, 256, 0, stream>>>(inputs, xm);
    proj_kernel<<<dim3(T / K2_TT, B), 256, 0, stream>>>(xm, proj_w, proj_b, y);
    band_fc_kernel<<<dim3(T / TT, B), 256, 0, stream>>>(y, fc_w, fc_b, out);
}